// Round 1
// baseline (288.850 us; speedup 1.0000x reference)
//
#include <hip/hip_runtime.h>
#include <stdint.h>

typedef unsigned short u16;
typedef __attribute__((ext_vector_type(4))) float f32x4;
typedef __attribute__((ext_vector_type(8))) __bf16 bf16x8;
typedef __attribute__((ext_vector_type(4))) u16 u16x4;

#define AS1 __attribute__((address_space(1)))
#define AS3 __attribute__((address_space(3)))
#define GLOAD_LDS16(gp, lp) \
  __builtin_amdgcn_global_load_lds((const AS1 void*)(gp), (AS3 void*)(lp), 16, 0, 0)

__device__ __forceinline__ u16 f2bf(float f) {
  union { float f; unsigned u; } v; v.f = f;
  return (u16)((v.u + 0x7FFFu + ((v.u >> 16) & 1u)) >> 16);
}

// ---------- fp32 -> bf16 conversion (Wq scaled by 1/sqrt(Dh)=0.125) ----------
__global__ __launch_bounds__(256) void convert_all(
    const float* __restrict__ x, const float* __restrict__ y,
    const float* __restrict__ wq, const float* __restrict__ wk,
    const float* __restrict__ wv, const float* __restrict__ wo,
    u16* __restrict__ xb, u16* __restrict__ yb, u16* __restrict__ wqb,
    u16* __restrict__ wkb, u16* __restrict__ wvb, u16* __restrict__ wob) {
  size_t i = (size_t)blockIdx.x * 256 + threadIdx.x;  // float4 index, 3M total
  const float* src; u16* dst; float scale = 1.0f; size_t off;
  if (i < (size_t)(1u << 20)) { src = x; dst = xb; off = i; }
  else if (i < (size_t)(2u << 20)) { src = y; dst = yb; off = i - (1u << 20); }
  else {
    size_t j = i - (size_t)(2u << 20);
    unsigned w = (unsigned)(j >> 18); off = j & ((1u << 18) - 1);
    if (w == 0)      { src = wq; dst = wqb; scale = 0.125f; }
    else if (w == 1) { src = wk; dst = wkb; }
    else if (w == 2) { src = wv; dst = wvb; }
    else             { src = wo; dst = wob; }
  }
  f32x4 v = ((const f32x4*)src)[off];
  u16x4 r;
  r.x = f2bf(v.x * scale); r.y = f2bf(v.y * scale);
  r.z = f2bf(v.z * scale); r.w = f2bf(v.w * scale);
  ((u16x4*)dst)[off] = r;
}

// ---------- BT-GEMM: C[m][n] = sum_k A[m][k] * Bt[n][k],  K = 1024 ----------
// 128x128 tile, 4 waves (2x2 of 64x64), 16x16x32 bf16 MFMA, BK = 32.
// MODE 0: C -> bf16 [B][H][S][64]   (Q/K projection; m = b*2048+s, n = h*64+dh)
// MODE 1: C -> bf16 [B][H][64][S]   (V^T projection; m = h*64+dh, n = b*2048+s)
// MODE 2: C -> fp32 row-major M x 1024 (final output)
template <int MODE>
__global__ __launch_bounds__(256, 2) void gemm_bt(
    const u16* __restrict__ A, const u16* __restrict__ Bt,
    void* __restrict__ C, int M, int N) {
  constexpr int K = 1024;
  __shared__ __align__(16) u16 As[128 * 32];
  __shared__ __align__(16) u16 Bs[128 * 32];
  const int tid = threadIdx.x;
  const int wave = tid >> 6, lane = tid & 63;
  const int l15 = lane & 15, quad = lane >> 4;
  const int tm = blockIdx.y * 128, tn = blockIdx.x * 128;
  const int wr = wave >> 1, wc = wave & 1;

  // staging: chunk g = wave*2 + c covers LDS bytes [g*1024, g*1024+1024)
  // lane l -> row = g*16 + l/4, col = (l%4)*8  (tile row-major [128][32])
  const int srow = wave * 32 + (lane >> 2);
  const int scol = (lane & 3) * 8;
  const u16* Ag = A + (size_t)(tm + srow) * K + scol;
  const u16* Bg = Bt + (size_t)(tn + srow) * K + scol;
  u16* Asl0 = &As[(wave * 2 + 0) * 512];
  u16* Asl1 = &As[(wave * 2 + 1) * 512];
  u16* Bsl0 = &Bs[(wave * 2 + 0) * 512];
  u16* Bsl1 = &Bs[(wave * 2 + 1) * 512];

  f32x4 acc[4][4] = {};

  for (int k0 = 0; k0 < K; k0 += 32) {
    __syncthreads();
    GLOAD_LDS16(Ag + k0, Asl0);
    GLOAD_LDS16(Ag + 16 * K + k0, Asl1);
    GLOAD_LDS16(Bg + k0, Bsl0);
    GLOAD_LDS16(Bg + 16 * K + k0, Bsl1);
    __syncthreads();
    bf16x8 af[4], bfr[4];
#pragma unroll
    for (int mi = 0; mi < 4; ++mi)
      af[mi] = *(const bf16x8*)&As[(wr * 64 + mi * 16 + l15) * 32 + quad * 8];
#pragma unroll
    for (int ni = 0; ni < 4; ++ni)
      bfr[ni] = *(const bf16x8*)&Bs[(wc * 64 + ni * 16 + l15) * 32 + quad * 8];
#pragma unroll
    for (int mi = 0; mi < 4; ++mi)
#pragma unroll
      for (int ni = 0; ni < 4; ++ni)
        acc[mi][ni] = __builtin_amdgcn_mfma_f32_16x16x32_bf16(
            af[mi], bfr[ni], acc[mi][ni], 0, 0, 0);
  }

#pragma unroll
  for (int mi = 0; mi < 4; ++mi) {
#pragma unroll
    for (int ni = 0; ni < 4; ++ni) {
#pragma unroll
      for (int r = 0; r < 4; ++r) {
        int gm = tm + wr * 64 + mi * 16 + quad * 4 + r;
        int gn = tn + wc * 64 + ni * 16 + l15;
        float val = acc[mi][ni][r];
        if (MODE == 0) {
          int b = gm >> 11, s = gm & 2047, h = gn >> 6, dh = gn & 63;
          ((u16*)C)[(((size_t)(b * 16 + h) * 2048 + s) << 6) + dh] = f2bf(val);
        } else if (MODE == 1) {
          int h = gm >> 6, dh = gm & 63, b = gn >> 11, s = gn & 2047;
          ((u16*)C)[(((size_t)(b * 16 + h) * 64 + dh) << 11) + s] = f2bf(val);
        } else {
          ((float*)C)[(size_t)gm * 1024 + gn] = val;
        }
      }
    }
  }
  (void)M; (void)N;
}

// ---------- flash-style attention, naive exp softmax (no max subtract) ----------
// grid (qt=16, h=16, b=2); 256 threads = 4 waves; wave owns 32 q-rows.
// Q pre-scaled by 1/8 (folded into Wq). den accumulated via all-ones B-frag MFMA.
__global__ __launch_bounds__(256, 2) void attn_kernel(
    const u16* __restrict__ Qw, const u16* __restrict__ Kw,
    const u16* __restrict__ Vtw, const float* __restrict__ mask,
    u16* __restrict__ Ow) {
  constexpr int S = 2048;
  __shared__ __align__(16) u16 Ks[128 * 64];    // [k-row][dh]
  __shared__ __align__(16) u16 Vs[64 * 128];    // [dh][k-row]  (V^T tile)
  __shared__ __align__(16) u16 Ps[128 * 136];   // padded: breaks write conflicts
  const int tid = threadIdx.x;
  const int wave = tid >> 6, lane = tid & 63;
  const int l15 = lane & 15, quad = lane >> 4;
  const int qt = blockIdx.x, h = blockIdx.y, b = blockIdx.z;
  const size_t head = ((size_t)(b * 16 + h)) * S * 64;

  // Q a-frags in registers: A[m=lane&15][k=quad*8+j]
  bf16x8 aq[2][2];
#pragma unroll
  for (int mi = 0; mi < 2; ++mi)
#pragma unroll
    for (int kq = 0; kq < 2; ++kq)
      aq[mi][kq] = *(const bf16x8*)&Qw[head +
          (size_t)(qt * 128 + wave * 32 + mi * 16 + l15) * 64 + kq * 32 + quad * 8];

  __bf16 one_bf = (__bf16)1.0f;
  bf16x8 ones = {one_bf, one_bf, one_bf, one_bf, one_bf, one_bf, one_bf, one_bf};

  f32x4 oa[2][4] = {};
  f32x4 den[2] = {};

  const int krow = lane >> 3, kcol = (lane & 7) * 8;    // K staging: 8 lanes/row
  const int vrow = lane >> 4, vcol = (lane & 15) * 8;   // Vt staging: 16 lanes/row

  for (int kt = 0; kt < S; kt += 128) {
    __syncthreads();
#pragma unroll
    for (int c = 0; c < 4; ++c) {
      int g = wave * 4 + c;
      GLOAD_LDS16(&Kw[head + (size_t)(kt + g * 8 + krow) * 64 + kcol], &Ks[g * 512]);
    }
#pragma unroll
    for (int c = 0; c < 4; ++c) {
      int g = wave * 4 + c;
      GLOAD_LDS16(&Vtw[head + (size_t)(g * 4 + vrow) * S + kt + vcol], &Vs[g * 512]);
    }
    __syncthreads();

    // S = Q K^T  (wave: 32 q-rows x 128 k-cols)
    f32x4 sa[2][8] = {};
#pragma unroll
    for (int kq = 0; kq < 2; ++kq) {
#pragma unroll
      for (int ni = 0; ni < 8; ++ni) {
        bf16x8 bk = *(const bf16x8*)&Ks[(ni * 16 + l15) * 64 + kq * 32 + quad * 8];
#pragma unroll
        for (int mi = 0; mi < 2; ++mi)
          sa[mi][ni] = __builtin_amdgcn_mfma_f32_16x16x32_bf16(
              aq[mi][kq], bk, sa[mi][ni], 0, 0, 0);
      }
    }

    // P = exp(S + mask) -> LDS bf16 (own rows only; no cross-wave barrier needed)
#pragma unroll
    for (int mi = 0; mi < 2; ++mi) {
#pragma unroll
      for (int ni = 0; ni < 8; ++ni) {
        int prow = wave * 32 + mi * 16 + quad * 4;
        int pcol = ni * 16 + l15;
        const float* mp = mask + (size_t)(qt * 128 + prow) * S + kt + pcol;
#pragma unroll
        for (int r = 0; r < 4; ++r) {
          float p = __expf(sa[mi][ni][r] + mp[(size_t)r * S]);
          Ps[(prow + r) * 136 + pcol] = f2bf(p);
        }
      }
    }

    // O += P @ V ; den += P @ ones
#pragma unroll
    for (int kq2 = 0; kq2 < 4; ++kq2) {
      bf16x8 ap[2];
#pragma unroll
      for (int mi = 0; mi < 2; ++mi)
        ap[mi] = *(const bf16x8*)&Ps[(wave * 32 + mi * 16 + l15) * 136 + kq2 * 32 + quad * 8];
#pragma unroll
      for (int ni = 0; ni < 4; ++ni) {
        bf16x8 bv = *(const bf16x8*)&Vs[(ni * 16 + l15) * 128 + kq2 * 32 + quad * 8];
#pragma unroll
        for (int mi = 0; mi < 2; ++mi)
          oa[mi][ni] = __builtin_amdgcn_mfma_f32_16x16x32_bf16(
              ap[mi], bv, oa[mi][ni], 0, 0, 0);
      }
#pragma unroll
      for (int mi = 0; mi < 2; ++mi)
        den[mi] = __builtin_amdgcn_mfma_f32_16x16x32_bf16(
            ap[mi], ones, den[mi], 0, 0, 0);
    }
  }

  // epilogue: O / (den + 1e-10) -> Ow [B][S][H*64] bf16
#pragma unroll
  for (int mi = 0; mi < 2; ++mi) {
#pragma unroll
    for (int ni = 0; ni < 4; ++ni) {
#pragma unroll
      for (int r = 0; r < 4; ++r) {
        int srow = qt * 128 + wave * 32 + mi * 16 + quad * 4 + r;
        int dh = ni * 16 + l15;
        float val = oa[mi][ni][r] / (den[mi][r] + 1e-10f);
        Ow[((size_t)(b * S + srow) << 10) + h * 64 + dh] = f2bf(val);
      }
    }
  }
}

extern "C" void kernel_launch(void* const* d_in, const int* in_sizes, int n_in,
                              void* d_out, int out_size, void* d_ws, size_t ws_size,
                              hipStream_t stream) {
  const float* x    = (const float*)d_in[0];
  const float* y    = (const float*)d_in[1];
  const float* mask = (const float*)d_in[2];
  const float* Wq   = (const float*)d_in[3];
  const float* Wk   = (const float*)d_in[4];
  const float* Wv   = (const float*)d_in[5];
  const float* Wo   = (const float*)d_in[6];
  char* ws = (char*)d_ws;
  const size_t MB = (size_t)1 << 20;
  u16* xb  = (u16*)(ws + 0  * MB);   // x bf16: 8 MB
  u16* yb  = (u16*)(ws + 8  * MB);   // y bf16: 8 MB
  u16* wqb = (u16*)(ws + 16 * MB);   // weights bf16: 2 MB each
  u16* wkb = (u16*)(ws + 18 * MB);
  u16* wvb = (u16*)(ws + 20 * MB);
  u16* wob = (u16*)(ws + 22 * MB);
  u16* Qw  = (u16*)(ws + 24 * MB);   // [B][H][S][64] bf16, scaled by 1/8
  u16* Kw  = (u16*)(ws + 32 * MB);   // [B][H][S][64] bf16
  u16* Vtw = (u16*)(ws + 40 * MB);   // [B][H][64][S] bf16
  u16* Ow  = (u16*)(ws + 48 * MB);   // [B][S][1024] bf16

  convert_all<<<12288, 256, 0, stream>>>(x, y, Wq, Wk, Wv, Wo,
                                         xb, yb, wqb, wkb, wvb, wob);
  gemm_bt<0><<<dim3(8, 32), 256, 0, stream>>>(yb, wqb, (void*)Qw, 4096, 1024);
  gemm_bt<0><<<dim3(8, 32), 256, 0, stream>>>(xb, wkb, (void*)Kw, 4096, 1024);
  gemm_bt<1><<<dim3(32, 8), 256, 0, stream>>>(wvb, xb, (void*)Vtw, 1024, 4096);
  attn_kernel<<<dim3(16, 16, 2), 256, 0, stream>>>(Qw, Kw, Vtw, mask, Ow);
  gemm_bt<2><<<dim3(8, 32), 256, 0, stream>>>(Ow, wob, d_out, 4096, 1024);
  (void)in_sizes; (void)n_in; (void)out_size; (void)ws_size;
}

// Round 2
// 267.462 us; speedup vs baseline: 1.0800x; 1.0800x over previous
//
#include <hip/hip_runtime.h>
#include <stdint.h>

typedef unsigned short u16;
typedef __attribute__((ext_vector_type(4))) float f32x4;
typedef __attribute__((ext_vector_type(2))) __bf16 bf16x2;
typedef __attribute__((ext_vector_type(8))) __bf16 bf16x8;
typedef __attribute__((ext_vector_type(4))) u16 u16x4;

#define AS1 __attribute__((address_space(1)))
#define AS3 __attribute__((address_space(3)))
#define GLOAD_LDS16(gp, lp) \
  __builtin_amdgcn_global_load_lds((const AS1 void*)(gp), (AS3 void*)(lp), 16, 0, 0)

__device__ __forceinline__ u16 f2bf(float f) {
  union { float f; unsigned u; } v; v.f = f;
  return (u16)((v.u + 0x7FFFu + ((v.u >> 16) & 1u)) >> 16);
}

__device__ __forceinline__ u16x4 pack4(float a, float b, float c, float d) {
#if __has_builtin(__builtin_amdgcn_cvt_pk_bf16_f32)
  union { struct { bf16x2 lo, hi; } p; u16x4 v; } u;
  u.p.lo = __builtin_amdgcn_cvt_pk_bf16_f32(a, b);
  u.p.hi = __builtin_amdgcn_cvt_pk_bf16_f32(c, d);
  return u.v;
#else
  u16x4 r; r.x = f2bf(a); r.y = f2bf(b); r.z = f2bf(c); r.w = f2bf(d); return r;
#endif
}

// ---------- fp32 -> bf16 conversion (Wq scaled by 1/sqrt(Dh)=0.125) ----------
__global__ __launch_bounds__(256) void convert_all(
    const float* __restrict__ x, const float* __restrict__ y,
    const float* __restrict__ wq, const float* __restrict__ wk,
    const float* __restrict__ wv, const float* __restrict__ wo,
    u16* __restrict__ xb, u16* __restrict__ yb, u16* __restrict__ wqb,
    u16* __restrict__ wkb, u16* __restrict__ wvb, u16* __restrict__ wob) {
  size_t i = (size_t)blockIdx.x * 256 + threadIdx.x;  // float4 index, 3M total
  const float* src; u16* dst; float scale = 1.0f; size_t off;
  if (i < (size_t)(1u << 20)) { src = x; dst = xb; off = i; }
  else if (i < (size_t)(2u << 20)) { src = y; dst = yb; off = i - (1u << 20); }
  else {
    size_t j = i - (size_t)(2u << 20);
    unsigned w = (unsigned)(j >> 18); off = j & ((1u << 18) - 1);
    if (w == 0)      { src = wq; dst = wqb; scale = 0.125f; }
    else if (w == 1) { src = wk; dst = wkb; }
    else if (w == 2) { src = wv; dst = wvb; }
    else             { src = wo; dst = wob; }
  }
  f32x4 v = ((const f32x4*)src)[off];
  ((u16x4*)dst)[off] = pack4(v.x * scale, v.y * scale, v.z * scale, v.w * scale);
}

// ---------- shared BT-GEMM core: 128x128 tile, K=1024, XOR-swizzled LDS ----------
// LDS tile: [128 rows][4 colblks of 16B], colblk stored at c ^ ((row>>1)&3).
// Read-side bank stride becomes conflict-free (2-way max).
__device__ __forceinline__ void gemm_core(
    const u16* __restrict__ A, const u16* __restrict__ Bt, int tm, int tn,
    u16* As, u16* Bs, f32x4 acc[4][4], int wave, int lane) {
  constexpr int K = 1024;
  const int l15 = lane & 15, quad = lane >> 4;
  const int wr = wave >> 1, wc = wave & 1;
  // staging: chunk g = wave*2+c covers rows g*16..g*16+15 (16 rows x 64B)
  const int srow = lane >> 2;                               // row within chunk
  const int scol = ((lane & 3) ^ ((lane >> 3) & 3)) * 8;    // swizzled src colblk
  const u16* Ag = A + (size_t)(tm + wave * 32 + srow) * K + scol;
  const u16* Bg = Bt + (size_t)(tn + wave * 32 + srow) * K + scol;
  u16* Asl0 = &As[(wave * 2 + 0) * 512];
  u16* Asl1 = &As[(wave * 2 + 1) * 512];
  u16* Bsl0 = &Bs[(wave * 2 + 0) * 512];
  u16* Bsl1 = &Bs[(wave * 2 + 1) * 512];
  const int rc = (quad ^ ((l15 >> 1) & 3)) * 8;             // swizzled read colblk

  for (int k0 = 0; k0 < K; k0 += 32) {
    __syncthreads();
    GLOAD_LDS16(Ag + k0, Asl0);
    GLOAD_LDS16(Ag + 16 * K + k0, Asl1);
    GLOAD_LDS16(Bg + k0, Bsl0);
    GLOAD_LDS16(Bg + 16 * K + k0, Bsl1);
    __syncthreads();
    bf16x8 af[4], bfr[4];
#pragma unroll
    for (int mi = 0; mi < 4; ++mi)
      af[mi] = *(const bf16x8*)&As[(wr * 64 + mi * 16 + l15) * 32 + rc];
#pragma unroll
    for (int ni = 0; ni < 4; ++ni)
      bfr[ni] = *(const bf16x8*)&Bs[(wc * 64 + ni * 16 + l15) * 32 + rc];
#pragma unroll
    for (int mi = 0; mi < 4; ++mi)
#pragma unroll
      for (int ni = 0; ni < 4; ++ni)
        acc[mi][ni] = __builtin_amdgcn_mfma_f32_16x16x32_bf16(
            af[mi], bfr[ni], acc[mi][ni], 0, 0, 0);
  }
}

// ---------- fused Q/K/Vt projections (z selects which) ----------
__global__ __launch_bounds__(256, 2) void qkv_gemm(
    const u16* __restrict__ xb, const u16* __restrict__ yb,
    const u16* __restrict__ wqb, const u16* __restrict__ wkb,
    const u16* __restrict__ wvb,
    u16* __restrict__ Qw, u16* __restrict__ Kw, u16* __restrict__ Vtw) {
  __shared__ __align__(16) u16 As[128 * 32];
  __shared__ __align__(16) u16 Bs[128 * 32];
  const int tid = threadIdx.x, wave = tid >> 6, lane = tid & 63;
  const int l15 = lane & 15, quad = lane >> 4;
  const int wr = wave >> 1, wc = wave & 1;
  const int z = blockIdx.z;
  const u16 *A, *Bt; int tm, tn;
  if (z == 0)      { A = yb;  Bt = wqb; tm = blockIdx.y * 128; tn = blockIdx.x * 128; }
  else if (z == 1) { A = xb;  Bt = wkb; tm = blockIdx.y * 128; tn = blockIdx.x * 128; }
  else             { A = wvb; Bt = xb;  tm = blockIdx.x * 128; tn = blockIdx.y * 128; }

  f32x4 acc[4][4] = {};
  gemm_core(A, Bt, tm, tn, As, Bs, acc, wave, lane);

#pragma unroll
  for (int mi = 0; mi < 4; ++mi) {
#pragma unroll
    for (int ni = 0; ni < 4; ++ni) {
#pragma unroll
      for (int r = 0; r < 4; ++r) {
        int gm = tm + wr * 64 + mi * 16 + quad * 4 + r;
        int gn = tn + wc * 64 + ni * 16 + l15;
        u16 val = f2bf(acc[mi][ni][r]);
        if (z == 2) {  // Vt: [B][H][64][S], gm = h*64+dh, gn = b*2048+s
          int h = gm >> 6, dh = gm & 63, b = gn >> 11, s = gn & 2047;
          Vtw[(((size_t)(b * 16 + h) * 64 + dh) << 11) + s] = val;
        } else {       // Q/K: [B][H][S][64], gm = b*2048+s, gn = h*64+dh
          int b = gm >> 11, s = gm & 2047, h = gn >> 6, dh = gn & 63;
          u16* dst = (z == 0) ? Qw : Kw;
          dst[(((size_t)(b * 16 + h) * 2048 + s) << 6) + dh] = val;
        }
      }
    }
  }
}

// ---------- output projection: fp32 out ----------
__global__ __launch_bounds__(256, 2) void out_gemm(
    const u16* __restrict__ Ow, const u16* __restrict__ wob,
    float* __restrict__ C) {
  __shared__ __align__(16) u16 As[128 * 32];
  __shared__ __align__(16) u16 Bs[128 * 32];
  const int tid = threadIdx.x, wave = tid >> 6, lane = tid & 63;
  const int l15 = lane & 15, quad = lane >> 4;
  const int wr = wave >> 1, wc = wave & 1;
  const int tm = blockIdx.y * 128, tn = blockIdx.x * 128;

  f32x4 acc[4][4] = {};
  gemm_core(Ow, wob, tm, tn, As, Bs, acc, wave, lane);

#pragma unroll
  for (int mi = 0; mi < 4; ++mi)
#pragma unroll
    for (int ni = 0; ni < 4; ++ni)
#pragma unroll
      for (int r = 0; r < 4; ++r) {
        int gm = tm + wr * 64 + mi * 16 + quad * 4 + r;
        int gn = tn + wc * 64 + ni * 16 + l15;
        C[(size_t)gm * 1024 + gn] = acc[mi][ni][r];
      }
}

// ---------- flash-style attention v2: S^T MFMA orientation ----------
// grid (qt=32, h=16, b=2); 256 threads = 4 waves; wave owns 16 q-rows.
// S^T = K·Q^T so C-layout gives 4 consecutive KEY columns per lane:
//   -> mask load = 1 dwordx4, P pack = 1 ds_write_b64, PV A-frag = ds_read_b128.
// K/V LDS XOR-swizzled (via swizzled global source addr in global_load_lds).
__global__ __launch_bounds__(256, 3) void attn_kernel(
    const u16* __restrict__ Qw, const u16* __restrict__ Kw,
    const u16* __restrict__ Vtw, const float* __restrict__ mask,
    u16* __restrict__ Ow) {
  constexpr int S = 2048;
  constexpr int PADK = 136;                    // 272B rows: 16B-aligned, 2-way banks
  __shared__ __align__(16) u16 Ks[128 * 64];   // [key r][8 cb16], cb stored at cb^(r&7)
  __shared__ __align__(16) u16 Vs[64 * 128];   // [dh r][16 cb16], cb stored at cb^(r&15)
  __shared__ __align__(16) u16 Ps[64 * PADK];  // [q][key] bf16
  const int tid = threadIdx.x;
  const int wave = tid >> 6, lane = tid & 63;
  const int l15 = lane & 15, quad = lane >> 4;
  const int qt = blockIdx.x, h = blockIdx.y, b = blockIdx.z;
  const size_t head = ((size_t)(b * 16 + h)) * S * 64;
  const int q_global = qt * 64 + wave * 16 + l15;

  // Q B-frags in registers (B[n=q=lane&15][k=quad*8+j]); Q pre-scaled by 1/8
  bf16x8 qf[2];
#pragma unroll
  for (int kq = 0; kq < 2; ++kq)
    qf[kq] = *(const bf16x8*)&Qw[head + (size_t)q_global * 64 + kq * 32 + quad * 8];

  const __bf16 one_bf = (__bf16)1.0f;
  const bf16x8 ones = {one_bf, one_bf, one_bf, one_bf, one_bf, one_bf, one_bf, one_bf};

  f32x4 oa[4] = {};
  f32x4 den = {};

  // K staging: chunk g (1KB) = rows g*8..+7; lane: row=g*8+(l>>3), src cb=(l&7)^((l>>3)&7)
  const int k_r = lane >> 3;
  const int k_c = ((lane & 7) ^ ((lane >> 3) & 7)) * 8;
  // V staging: chunk g (1KB) = dh rows g*4..+3; lane: dh=g*4+(l>>4), src cb=(l&15)^(dh&15)
  const int v_r = lane >> 4;
  const int v_cbase = lane & 15;
  const float* mrow = mask + (size_t)q_global * S;

  for (int kt = 0; kt < S; kt += 128) {
    __syncthreads();
#pragma unroll
    for (int c = 0; c < 4; ++c) {
      int g = wave * 4 + c;
      GLOAD_LDS16(&Kw[head + (size_t)(kt + g * 8 + k_r) * 64 + k_c], &Ks[g * 512]);
    }
#pragma unroll
    for (int c = 0; c < 4; ++c) {
      int g = wave * 4 + c;
      int dh = g * 4 + v_r;
      int scb = (v_cbase ^ (dh & 15)) * 8;
      GLOAD_LDS16(&Vtw[head + (size_t)dh * S + kt + scb], &Vs[g * 512]);
    }
    // mask prefetch (independent of LDS staging; drained by the same barrier)
    f32x4 mv[8];
#pragma unroll
    for (int mk = 0; mk < 8; ++mk)
      mv[mk] = *(const f32x4*)&mrow[kt + mk * 16 + quad * 4];
    __syncthreads();

    // S^T = K·Q^T : D[m=key][n=query]; 8 key-tiles x 1 query-tile
    f32x4 sa[8] = {};
#pragma unroll
    for (int kq = 0; kq < 2; ++kq) {
#pragma unroll
      for (int mk = 0; mk < 8; ++mk) {
        int row = mk * 16 + l15;
        bf16x8 ak = *(const bf16x8*)&Ks[row * 64 + (((kq * 4 + quad) ^ (l15 & 7)) * 8)];
        sa[mk] = __builtin_amdgcn_mfma_f32_16x16x32_bf16(ak, qf[kq], sa[mk], 0, 0, 0);
      }
    }

    // P = exp(S + mask): lane holds 4 consecutive keys for query l15
#pragma unroll
    for (int mk = 0; mk < 8; ++mk) {
      float p0 = __expf(sa[mk][0] + mv[mk][0]);
      float p1 = __expf(sa[mk][1] + mv[mk][1]);
      float p2 = __expf(sa[mk][2] + mv[mk][2]);
      float p3 = __expf(sa[mk][3] + mv[mk][3]);
      *(u16x4*)&Ps[(wave * 16 + l15) * PADK + mk * 16 + quad * 4] = pack4(p0, p1, p2, p3);
    }

    // O += P·V ; den += P·1  (P rows wave-exclusive: no barrier needed)
#pragma unroll
    for (int kq2 = 0; kq2 < 4; ++kq2) {
      bf16x8 ap = *(const bf16x8*)&Ps[(wave * 16 + l15) * PADK + kq2 * 32 + quad * 8];
#pragma unroll
      for (int nv = 0; nv < 4; ++nv) {
        int row = nv * 16 + l15;
        bf16x8 bv = *(const bf16x8*)&Vs[row * 128 + (((kq2 * 4 + quad) ^ l15) * 8)];
        oa[nv] = __builtin_amdgcn_mfma_f32_16x16x32_bf16(ap, bv, oa[nv], 0, 0, 0);
      }
      den = __builtin_amdgcn_mfma_f32_16x16x32_bf16(ap, ones, den, 0, 0, 0);
    }
  }

  // epilogue: D[m=q][n=dh]; row = quad*4+r, col = l15
#pragma unroll
  for (int nv = 0; nv < 4; ++nv) {
#pragma unroll
    for (int r = 0; r < 4; ++r) {
      int srow = qt * 64 + wave * 16 + quad * 4 + r;
      int dh = nv * 16 + l15;
      float val = oa[nv][r] / (den[r] + 1e-10f);
      Ow[((size_t)(b * S + srow) << 10) + h * 64 + dh] = f2bf(val);
    }
  }
}

extern "C" void kernel_launch(void* const* d_in, const int* in_sizes, int n_in,
                              void* d_out, int out_size, void* d_ws, size_t ws_size,
                              hipStream_t stream) {
  const float* x    = (const float*)d_in[0];
  const float* y    = (const float*)d_in[1];
  const float* mask = (const float*)d_in[2];
  const float* Wq   = (const float*)d_in[3];
  const float* Wk   = (const float*)d_in[4];
  const float* Wv   = (const float*)d_in[5];
  const float* Wo   = (const float*)d_in[6];
  char* ws = (char*)d_ws;
  const size_t MB = (size_t)1 << 20;
  u16* xb  = (u16*)(ws + 0  * MB);
  u16* yb  = (u16*)(ws + 8  * MB);
  u16* wqb = (u16*)(ws + 16 * MB);
  u16* wkb = (u16*)(ws + 18 * MB);
  u16* wvb = (u16*)(ws + 20 * MB);
  u16* wob = (u16*)(ws + 22 * MB);
  u16* Qw  = (u16*)(ws + 24 * MB);   // [B][H][S][64] bf16, scaled by 1/8
  u16* Kw  = (u16*)(ws + 32 * MB);   // [B][H][S][64] bf16
  u16* Vtw = (u16*)(ws + 40 * MB);   // [B][H][64][S] bf16
  u16* Ow  = (u16*)(ws + 48 * MB);   // [B][S][1024] bf16

  convert_all<<<12288, 256, 0, stream>>>(x, y, Wq, Wk, Wv, Wo,
                                         xb, yb, wqb, wkb, wvb, wob);
  qkv_gemm<<<dim3(8, 32, 3), 256, 0, stream>>>(xb, yb, wqb, wkb, wvb, Qw, Kw, Vtw);
  attn_kernel<<<dim3(32, 16, 2), 256, 0, stream>>>(Qw, Kw, Vtw, mask, Ow);
  out_gemm<<<dim3(8, 32), 256, 0, stream>>>(Ow, wob, (float*)d_out);
  (void)in_sizes; (void)n_in; (void)out_size; (void)ws_size;
}

// Round 3
// 246.322 us; speedup vs baseline: 1.1727x; 1.0858x over previous
//
#include <hip/hip_runtime.h>
#include <stdint.h>

typedef unsigned short u16;
typedef __attribute__((ext_vector_type(4))) float f32x4;
typedef __attribute__((ext_vector_type(2))) __bf16 bf16x2;
typedef __attribute__((ext_vector_type(8))) __bf16 bf16x8;
typedef __attribute__((ext_vector_type(4))) u16 u16x4;

#define AS1 __attribute__((address_space(1)))
#define AS3 __attribute__((address_space(3)))
#define GLOAD_LDS16(gp, lp) \
  __builtin_amdgcn_global_load_lds((const AS1 void*)(gp), (AS3 void*)(lp), 16, 0, 0)

__device__ __forceinline__ u16 f2bf(float f) {
  union { float f; unsigned u; } v; v.f = f;
  return (u16)((v.u + 0x7FFFu + ((v.u >> 16) & 1u)) >> 16);
}
__device__ __forceinline__ float bf2f(u16 u) {
  union { unsigned u; float f; } v; v.u = ((unsigned)u) << 16; return v.f;
}
__device__ __forceinline__ float fexp2(float x) {
#if __has_builtin(__builtin_amdgcn_exp2f)
  return __builtin_amdgcn_exp2f(x);
#else
  return exp2f(x);
#endif
}
__device__ __forceinline__ u16x4 pack4(float a, float b, float c, float d) {
#if __has_builtin(__builtin_amdgcn_cvt_pk_bf16_f32)
  union { struct { bf16x2 lo, hi; } p; u16x4 v; } u;
  u.p.lo = __builtin_amdgcn_cvt_pk_bf16_f32(a, b);
  u.p.hi = __builtin_amdgcn_cvt_pk_bf16_f32(c, d);
  return u.v;
#else
  u16x4 r; r.x = f2bf(a); r.y = f2bf(b); r.z = f2bf(c); r.w = f2bf(d); return r;
#endif
}

#define LOG2E 1.44269504f

// ---------- fp32 -> bf16 conversion ----------
// Wq scaled by log2e/8 (fold softmax 1/sqrt(64) + exp2 domain); mask scaled by log2e.
__global__ __launch_bounds__(256) void convert_all(
    const float* __restrict__ x, const float* __restrict__ y,
    const float* __restrict__ wq, const float* __restrict__ wk,
    const float* __restrict__ wv, const float* __restrict__ wo,
    const float* __restrict__ mask,
    u16* __restrict__ xb, u16* __restrict__ yb, u16* __restrict__ wqb,
    u16* __restrict__ wkb, u16* __restrict__ wvb, u16* __restrict__ wob,
    u16* __restrict__ maskb) {
  size_t i = (size_t)blockIdx.x * 256 + threadIdx.x;  // float4 index, 4M total
  const float* src; u16* dst; float scale = 1.0f; size_t off;
  if (i < (size_t)(1u << 20)) { src = x; dst = xb; off = i; }
  else if (i < (size_t)(2u << 20)) { src = y; dst = yb; off = i - (1u << 20); }
  else if (i < (size_t)(3u << 20)) {
    size_t j = i - (size_t)(2u << 20);
    unsigned w = (unsigned)(j >> 18); off = j & ((1u << 18) - 1);
    if (w == 0)      { src = wq; dst = wqb; scale = 0.125f * LOG2E; }
    else if (w == 1) { src = wk; dst = wkb; }
    else if (w == 2) { src = wv; dst = wvb; }
    else             { src = wo; dst = wob; }
  } else { src = mask; dst = maskb; scale = LOG2E; off = i - (size_t)(3u << 20); }
  f32x4 v = ((const f32x4*)src)[off];
  ((u16x4*)dst)[off] = pack4(v.x * scale, v.y * scale, v.z * scale, v.w * scale);
}

// ---------- BT-GEMM core: 128x128 tile, K=1024, BK=64, XOR-swizzled LDS ----------
// LDS tile [128 r][8 colblks of 16B]; global colblk c of row r stored at slot c^(r&7).
__device__ __forceinline__ void gemm_core64(
    const u16* __restrict__ A, const u16* __restrict__ Bt, int tm, int tn,
    u16* As, u16* Bs, f32x4 acc[4][4], int wave, int lane) {
  constexpr int K = 1024;
  const int l15 = lane & 15, quad = lane >> 4;
  const int wr = wave >> 1, wc = wave & 1;
  // staging: chunk g = wave*4+c covers rows g*8..+7; lane: row g*8+(l>>3),
  // LDS slot l&7 <- global colblk (l&7)^((l>>3)&7)
  const int srow = lane >> 3;
  const int scol = ((lane & 7) ^ (srow & 7)) * 8;
  const u16* Ag = A + (size_t)(tm + wave * 32 + srow) * K + scol;
  const u16* Bg = Bt + (size_t)(tn + wave * 32 + srow) * K + scol;
  const int rsw = l15 & 7;  // read swizzle

  for (int k0 = 0; k0 < K; k0 += 64) {
    __syncthreads();
#pragma unroll
    for (int c = 0; c < 4; ++c)
      GLOAD_LDS16(Ag + (size_t)c * 8 * K + k0, &As[(wave * 4 + c) * 512]);
#pragma unroll
    for (int c = 0; c < 4; ++c)
      GLOAD_LDS16(Bg + (size_t)c * 8 * K + k0, &Bs[(wave * 4 + c) * 512]);
    __syncthreads();
#pragma unroll
    for (int kq = 0; kq < 2; ++kq) {
      bf16x8 af[4], bfr[4];
#pragma unroll
      for (int mi = 0; mi < 4; ++mi)
        af[mi] = *(const bf16x8*)&As[(wr * 64 + mi * 16 + l15) * 64 +
                                     ((kq * 4 + quad) ^ rsw) * 8];
#pragma unroll
      for (int ni = 0; ni < 4; ++ni)
        bfr[ni] = *(const bf16x8*)&Bs[(wc * 64 + ni * 16 + l15) * 64 +
                                      ((kq * 4 + quad) ^ rsw) * 8];
#pragma unroll
      for (int mi = 0; mi < 4; ++mi)
#pragma unroll
        for (int ni = 0; ni < 4; ++ni)
          acc[mi][ni] = __builtin_amdgcn_mfma_f32_16x16x32_bf16(
              af[mi], bfr[ni], acc[mi][ni], 0, 0, 0);
    }
  }
}

// ---------- fused Q/K/Vt projections (z selects which) ----------
__global__ __launch_bounds__(256, 3) void qkv_gemm(
    const u16* __restrict__ xb, const u16* __restrict__ yb,
    const u16* __restrict__ wqb, const u16* __restrict__ wkb,
    const u16* __restrict__ wvb,
    u16* __restrict__ Qw, u16* __restrict__ Kw, u16* __restrict__ Vtw) {
  __shared__ __align__(16) u16 As[128 * 64];
  __shared__ __align__(16) u16 Bs[128 * 64];
  const int tid = threadIdx.x, wave = tid >> 6, lane = tid & 63;
  const int l15 = lane & 15, quad = lane >> 4;
  const int wr = wave >> 1, wc = wave & 1;
  const int z = blockIdx.z;
  const u16 *A, *Bt; int tm, tn;
  if (z == 0)      { A = yb;  Bt = wqb; tm = blockIdx.y * 128; tn = blockIdx.x * 128; }
  else if (z == 1) { A = xb;  Bt = wkb; tm = blockIdx.y * 128; tn = blockIdx.x * 128; }
  else             { A = wvb; Bt = xb;  tm = blockIdx.x * 128; tn = blockIdx.y * 128; }

  f32x4 acc[4][4] = {};
  gemm_core64(A, Bt, tm, tn, As, Bs, acc, wave, lane);

#pragma unroll
  for (int mi = 0; mi < 4; ++mi) {
#pragma unroll
    for (int ni = 0; ni < 4; ++ni) {
#pragma unroll
      for (int r = 0; r < 4; ++r) {
        int gm = tm + wr * 64 + mi * 16 + quad * 4 + r;
        int gn = tn + wc * 64 + ni * 16 + l15;
        u16 val = f2bf(acc[mi][ni][r]);
        if (z == 2) {  // Vt: [B][H][64][S]
          int h = gm >> 6, dh = gm & 63, b = gn >> 11, s = gn & 2047;
          Vtw[(((size_t)(b * 16 + h) * 64 + dh) << 11) + s] = val;
        } else {       // Q/K: [B][H][S][64]
          int b = gm >> 11, s = gm & 2047, h = gn >> 6, dh = gn & 63;
          u16* dst = (z == 0) ? Qw : Kw;
          dst[(((size_t)(b * 16 + h) * 2048 + s) << 6) + dh] = val;
        }
      }
    }
  }
}

// ---------- output projection: fp32 out ----------
__global__ __launch_bounds__(256, 3) void out_gemm(
    const u16* __restrict__ Ow, const u16* __restrict__ wob,
    float* __restrict__ C) {
  __shared__ __align__(16) u16 As[128 * 64];
  __shared__ __align__(16) u16 Bs[128 * 64];
  const int tid = threadIdx.x, wave = tid >> 6, lane = tid & 63;
  const int l15 = lane & 15, quad = lane >> 4;
  const int wr = wave >> 1, wc = wave & 1;
  const int tm = blockIdx.y * 128, tn = blockIdx.x * 128;

  f32x4 acc[4][4] = {};
  gemm_core64(Ow, wob, tm, tn, As, Bs, acc, wave, lane);

#pragma unroll
  for (int mi = 0; mi < 4; ++mi)
#pragma unroll
    for (int ni = 0; ni < 4; ++ni)
#pragma unroll
      for (int r = 0; r < 4; ++r) {
        int gm = tm + wr * 64 + mi * 16 + quad * 4 + r;
        int gn = tn + wc * 64 + ni * 16 + l15;
        C[(size_t)gm * 1024 + gn] = acc[mi][ni][r];
      }
}

// ---------- flash-style attention v3 ----------
// 128 q/block, 4 waves x 32 q (2 q-tiles), kt=128, S^T orientation.
// grid (qt=16, h=16, b=2) = 512 blocks. exp2 domain (Wq & mask pre-scaled log2e).
// K/V staged swizzled via global_load_lds; P round-trips LDS (padded 136).
__global__ __launch_bounds__(256, 2) void attn_kernel(
    const u16* __restrict__ Qw, const u16* __restrict__ Kw,
    const u16* __restrict__ Vtw, const u16* __restrict__ maskb,
    u16* __restrict__ Ow) {
  constexpr int S = 2048;
  constexpr int PADK = 136;
  __shared__ __align__(16) u16 Ks[128 * 64];   // [key][8 cb16], cb c at slot c^(key&7)
  __shared__ __align__(16) u16 Vs[64 * 128];   // [dh][16 cb16], cb c at slot c^(dh&15)
  __shared__ __align__(16) u16 Ps[128 * PADK]; // [q][key] bf16
  const int tid = threadIdx.x;
  const int wave = tid >> 6, lane = tid & 63;
  const int l15 = lane & 15, quad = lane >> 4;
  const int h = blockIdx.y, b = blockIdx.z;
  const size_t head = ((size_t)(b * 16 + h)) * S * 64;
  const int qbase = blockIdx.x * 128 + wave * 32;  // wave owns 32 q-rows

  // Q B-frags in registers: B[n=q=l15][k=quad*8+j]
  bf16x8 qf[2][2];
#pragma unroll
  for (int q2 = 0; q2 < 2; ++q2)
#pragma unroll
    for (int kq = 0; kq < 2; ++kq)
      qf[q2][kq] = *(const bf16x8*)&Qw[head +
          (size_t)(qbase + q2 * 16 + l15) * 64 + kq * 32 + quad * 8];

  const __bf16 one_bf = (__bf16)1.0f;
  const bf16x8 ones = {one_bf, one_bf, one_bf, one_bf, one_bf, one_bf, one_bf, one_bf};

  f32x4 oa[2][4] = {};
  f32x4 den[2] = {};

  // K staging: chunk g = keys g*8..+7; lane: key=g*8+(l>>3), slot l&7 <- cb (l&7)^((l>>3)&7)
  const int k_key = lane >> 3;
  const int k_c = ((lane & 7) ^ (k_key & 7)) * 8;
  // V staging: chunk g = dh g*4..+3; lane: dh=g*4+(l>>4), slot l&15 <- cb (l&15)^(dh&15)
  const int v_dh = lane >> 4;
  const int v_cl = lane & 15;
  const u16* mrow[2] = { maskb + (size_t)(qbase + l15) * S,
                         maskb + (size_t)(qbase + 16 + l15) * S };

  for (int kt = 0; kt < S; kt += 128) {
    __syncthreads();
#pragma unroll
    for (int c = 0; c < 4; ++c) {
      int g = wave * 4 + c;
      GLOAD_LDS16(&Kw[head + (size_t)(kt + g * 8 + k_key) * 64 + k_c], &Ks[g * 512]);
    }
#pragma unroll
    for (int c = 0; c < 4; ++c) {
      int g = wave * 4 + c;
      int dh = g * 4 + v_dh;
      GLOAD_LDS16(&Vtw[head + (size_t)dh * S + kt + ((v_cl ^ (dh & 15)) * 8)],
                  &Vs[g * 512]);
    }
    // mask loads (bf16, pre-scaled by log2e): 4 consecutive keys per lane
    u16x4 mq[2][8];
#pragma unroll
    for (int q2 = 0; q2 < 2; ++q2)
#pragma unroll
      for (int mk = 0; mk < 8; ++mk)
        mq[q2][mk] = *(const u16x4*)&mrow[q2][kt + mk * 16 + quad * 4];
    __syncthreads();

    // S^T = K·Q^T : m=key (8 tiles), n=query (2 tiles); A-frag shared across q-tiles
    f32x4 sa[2][8] = {};
#pragma unroll
    for (int kq = 0; kq < 2; ++kq) {
#pragma unroll
      for (int mk = 0; mk < 8; ++mk) {
        bf16x8 ak = *(const bf16x8*)&Ks[(mk * 16 + l15) * 64 +
                                        ((kq * 4 + quad) ^ (l15 & 7)) * 8];
        sa[0][mk] = __builtin_amdgcn_mfma_f32_16x16x32_bf16(ak, qf[0][kq], sa[0][mk], 0, 0, 0);
        sa[1][mk] = __builtin_amdgcn_mfma_f32_16x16x32_bf16(ak, qf[1][kq], sa[1][mk], 0, 0, 0);
      }
    }

    // P = exp2(S + mask) -> Ps (wave-exclusive rows; no barrier needed)
#pragma unroll
    for (int q2 = 0; q2 < 2; ++q2) {
#pragma unroll
      for (int mk = 0; mk < 8; ++mk) {
        float p0 = fexp2(sa[q2][mk][0] + bf2f(mq[q2][mk].x));
        float p1 = fexp2(sa[q2][mk][1] + bf2f(mq[q2][mk].y));
        float p2 = fexp2(sa[q2][mk][2] + bf2f(mq[q2][mk].z));
        float p3 = fexp2(sa[q2][mk][3] + bf2f(mq[q2][mk].w));
        *(u16x4*)&Ps[(wave * 32 + q2 * 16 + l15) * PADK + mk * 16 + quad * 4] =
            pack4(p0, p1, p2, p3);
      }
    }

    // O += P·V ; den += P·1
#pragma unroll
    for (int kq2 = 0; kq2 < 4; ++kq2) {
      bf16x8 ap0 = *(const bf16x8*)&Ps[(wave * 32 + l15) * PADK + kq2 * 32 + quad * 8];
      bf16x8 ap1 = *(const bf16x8*)&Ps[(wave * 32 + 16 + l15) * PADK + kq2 * 32 + quad * 8];
#pragma unroll
      for (int nv = 0; nv < 4; ++nv) {
        bf16x8 bv = *(const bf16x8*)&Vs[(nv * 16 + l15) * 128 +
                                        ((kq2 * 4 + quad) ^ l15) * 8];
        oa[0][nv] = __builtin_amdgcn_mfma_f32_16x16x32_bf16(ap0, bv, oa[0][nv], 0, 0, 0);
        oa[1][nv] = __builtin_amdgcn_mfma_f32_16x16x32_bf16(ap1, bv, oa[1][nv], 0, 0, 0);
      }
      den[0] = __builtin_amdgcn_mfma_f32_16x16x32_bf16(ap0, ones, den[0], 0, 0, 0);
      den[1] = __builtin_amdgcn_mfma_f32_16x16x32_bf16(ap1, ones, den[1], 0, 0, 0);
    }
  }

  // epilogue: O / (den + 1e-10) -> Ow [B][S][H*64] bf16
#pragma unroll
  for (int q2 = 0; q2 < 2; ++q2) {
#pragma unroll
    for (int nv = 0; nv < 4; ++nv) {
#pragma unroll
      for (int r = 0; r < 4; ++r) {
        int srow = qbase + q2 * 16 + quad * 4 + r;
        int dh = nv * 16 + l15;
        float val = oa[q2][nv][r] / (den[q2][r] + 1e-10f);
        Ow[((size_t)(b * S + srow) << 10) + h * 64 + dh] = f2bf(val);
      }
    }
  }
}

extern "C" void kernel_launch(void* const* d_in, const int* in_sizes, int n_in,
                              void* d_out, int out_size, void* d_ws, size_t ws_size,
                              hipStream_t stream) {
  const float* x    = (const float*)d_in[0];
  const float* y    = (const float*)d_in[1];
  const float* mask = (const float*)d_in[2];
  const float* Wq   = (const float*)d_in[3];
  const float* Wk   = (const float*)d_in[4];
  const float* Wv   = (const float*)d_in[5];
  const float* Wo   = (const float*)d_in[6];
  char* ws = (char*)d_ws;
  const size_t MB = (size_t)1 << 20;
  u16* xb  = (u16*)(ws + 0  * MB);
  u16* yb  = (u16*)(ws + 8  * MB);
  u16* wqb = (u16*)(ws + 16 * MB);
  u16* wkb = (u16*)(ws + 18 * MB);
  u16* wvb = (u16*)(ws + 20 * MB);
  u16* wob = (u16*)(ws + 22 * MB);
  u16* Qw  = (u16*)(ws + 24 * MB);   // [B][H][S][64] bf16, scaled log2e/8
  u16* Kw  = (u16*)(ws + 32 * MB);   // [B][H][S][64] bf16
  u16* Vtw = (u16*)(ws + 40 * MB);   // [B][H][64][S] bf16
  u16* Ow  = (u16*)(ws + 48 * MB);   // [B][S][1024] bf16
  // mask bf16 (8 MB) lives in d_out scratch: consumed by attn, then out_gemm
  // overwrites d_out last (stream-ordered).
  u16* maskb = (u16*)d_out;

  convert_all<<<16384, 256, 0, stream>>>(x, y, Wq, Wk, Wv, Wo, mask,
                                         xb, yb, wqb, wkb, wvb, wob, maskb);
  qkv_gemm<<<dim3(8, 32, 3), 256, 0, stream>>>(xb, yb, wqb, wkb, wvb, Qw, Kw, Vtw);
  attn_kernel<<<dim3(16, 16, 2), 256, 0, stream>>>(Qw, Kw, Vtw, maskb, Ow);
  out_gemm<<<dim3(8, 32), 256, 0, stream>>>(Ow, wob, (float*)d_out);
  (void)in_sizes; (void)n_in; (void)out_size; (void)ws_size;
}